// Round 12
// baseline (403.156 us; speedup 1.0000x reference)
//
#include <hip/hip_runtime.h>
#include <math.h>

// SemiCurrSinkhornKnopp_stable on MI355X: persistent kernel, no global barrier.
// R12 = R11 (register-cached K, overlapped consensus poll, dual-rep row sums,
// tagged consensus ring, per-batch leaf arrive) + REP 8 -> 32. The colsum
// atomicAdd burst serializes per LLC line (~124 RMW/line at REP=8); REP=32
// spreads the same adds over 4x the lines (~31 RMW/line), shortening the
// vmcnt-drain tail that precedes the arrive. Zero/guard logic updated for the
// bigger scratch (done-wait now guards slabs >= 51 of batch 3).

#define NWG   256
#define NTHR  512
#define NW    8
#define NROW  2048
#define KC    512
#define KP1   513
#define RPW   32
#define REP   32
#define PARF  (4 * REP * KP1)   // 65664 floats per parity
#define EPSI  0.1f
#define IEPS  10.0f
#define FI    0.90909090909090906f
#define FIM1  (-0.09090909090909094f)
#define TINY  1.1920928955078125e-07f
#define PA    (1.0f/2048.0f)
#define PBR   (0.5f/512.0f)
#define PBS   0.5f
#define STABT 1.0e8f
#define STOPE 1.0e-6f
#define ITMAX 50

#define AST(p, v)  __hip_atomic_store((p), (v), __ATOMIC_RELAXED, __HIP_MEMORY_SCOPE_AGENT)
#define ALD(p)     __hip_atomic_load((p), __ATOMIC_RELAXED, __HIP_MEMORY_SCOPE_AGENT)
#define AADD(p, v) __hip_atomic_fetch_add((p), (v), __ATOMIC_RELAXED, __HIP_MEMORY_SCOPE_AGENT)

// d_ws layout: leaf @0 (16x64B) | cons @2048 (4b x 4slot x 8grp x 64B = 8192)
//              amaxa @10240 ([2][256] f32) | done @12288
#define WS_ZERO 12352

// colsum scratch carved from d_out tail: [3][4][REP][KP1] floats
#define TOT_OUT    4194304
#define SCR_FLOATS (3 * PARF)            // 196992
#define SCR_OFF    (TOT_OUT - SCR_FLOATS)

__device__ __forceinline__ float wsum(float v) {
#pragma unroll
  for (int m = 32; m > 0; m >>= 1) v += __shfl_xor(v, m, 64);
  return v;
}
__device__ __forceinline__ float wmaxf(float v) {
#pragma unroll
  for (int m = 32; m > 0; m >>= 1) v = fmaxf(v, __shfl_xor(v, m, 64));
  return v;
}

__global__ __launch_bounds__(NTHR)
void sinkhorn_kernel(const float* __restrict__ logits, float* out,
                     unsigned char* ws, float* colsum) {
  const int tid  = threadIdx.x;
  const int wg   = blockIdx.x;
  const int lane = tid & 63;
  const int wid  = tid >> 6;
  const int bat  = wg >> 6;
  const int slab = wg & 63;
  const int rep  = slab & (REP - 1);
  const int grp  = wg & 7;

  unsigned*           leafA = (unsigned*)(ws);
  unsigned long long* cons  = (unsigned long long*)(ws + 2048);
  float*              amaxa = (float*)(ws + 10240);
  unsigned*           done  = (unsigned*)(ws + 12288);

  __shared__ float Klds[RPW][KP1];
  __shared__ float evn[KP1], evE[KP1], vv[KP1], bb[KP1], ww[KC];
  __shared__ __align__(16) float alp[RPW];
  __shared__ float sN[RPW], sE[RPW], a_s[RPW], kap[RPW];
  __shared__ float redS[NW], redM[NW];
  __shared__ float c_es, c_mx;

  // ---------------- init own-batch state ----------------
  for (int j = tid; j < KP1; j += NTHR) {
    vv[j] = 0.f; bb[j] = 1.f / 513.f;
    evE[j] = 1.f; evn[j] = 1.f / 513.f;          // E(vv=0)=1
  }
  for (int j = tid; j < KC; j += NTHR) ww[j] = 1.f;
  if (tid < RPW) { kap[tid] = 1.f; a_s[tid] = 0.f; alp[tid] = 0.f; }

  // ---------------- build K = softmax(logits)^10 in LDS ----------------
  const size_t rowg0 = (size_t)bat * NROW + (size_t)slab * RPW;
  for (int r = wid; r < RPW; r += NW) {
    const float* lp = logits + (rowg0 + (size_t)r) * KC;
    float x[8];
    float mx = -INFINITY;
#pragma unroll
    for (int m = 0; m < 8; ++m) { x[m] = lp[lane + (m << 6)]; mx = fmaxf(mx, x[m]); }
    mx = wmaxf(mx);
    float sm = 0.f;
#pragma unroll
    for (int m = 0; m < 8; ++m) sm += expf(x[m] - mx);
    sm = wsum(sm);
    float lse = mx + logf(sm);
#pragma unroll
    for (int m = 0; m < 8; ++m) Klds[r][lane + (m << 6)] = expf((x[m] - lse) * IEPS);
    if (lane == 0) Klds[r][KC] = 1.f;
  }
  __syncthreads();

  // ---------------- cache K in registers (iteration-invariant) ----------------
  const int rs = (wid - 1) * 5;     // rows for waves 1..7 (5,5,5,5,5,5,2)
  float Kr[5][8];
  if (wid >= 1) {
#pragma unroll
    for (int q = 0; q < 5; ++q) {
      const int r = rs + q;
      if (r < RPW) {
#pragma unroll
        for (int m = 0; m < 8; ++m) Kr[q][m] = Klds[r][lane + (m << 6)];
      }
    }
  }
  float Kc[RPW];                    // column `tid` (tid<512; col 512 is all-ones)
#pragma unroll
  for (int r = 0; r < RPW; ++r) Kc[r] = Klds[r][tid];

  int stabled = 0;
  int p = 0;
  bool broke = false;

  for (int t = 0; t < ITMAX; ++t) {
    const int p2 = t & 1;
    const int pn = (p == 2) ? 0 : (p + 1);

    // ---- S1: wave0 polls cons(t-1) || waves1-7 register dual-rep row dots ----
    if (wid == 0) {
      if (t > 0) {
        const unsigned tag = (unsigned)t;
        const int slot = t & 3;
        const unsigned long long* ln =
            &cons[(size_t)(((lane & 3) * 4 + slot) * 8 + grp) * 8];
        unsigned long long e = 0, m = 0;
        bool rdy = (lane >= 4);
        for (;;) {
          if (!rdy) {
            e = ALD(&ln[0]); m = ALD(&ln[1]);
            rdy = ((unsigned)(e >> 32) == tag) && ((unsigned)(m >> 32) == tag);
          }
          if (__all(rdy)) break;
          __builtin_amdgcn_s_sleep(1);
        }
        float ef = (lane < 4) ? __uint_as_float((unsigned)e) : 0.f;
        float mf = (lane < 4) ? __uint_as_float((unsigned)m) : 0.f;
        ef += __shfl_xor(ef, 1, 64); ef += __shfl_xor(ef, 2, 64);
        mf = fmaxf(mf, __shfl_xor(mf, 1, 64)); mf = fmaxf(mf, __shfl_xor(mf, 2, 64));
        if (lane == 0) { c_es = ef; c_mx = mf; }
      }
    } else {
      float en[8], eE[8];
#pragma unroll
      for (int m = 0; m < 8; ++m) {
        const int j = lane + (m << 6);
        en[m] = evn[j]; eE[m] = evE[j];
      }
      const float enS = evn[KC], eES = evE[KC];    // slack (K=1), broadcast
#pragma unroll
      for (int q = 0; q < 5; ++q) {
        const int r = rs + q;
        if (r < RPW) {
          float sn = 0.f, se = 0.f;
#pragma unroll
          for (int m = 0; m < 8; ++m) { sn += Kr[q][m] * en[m]; se += Kr[q][m] * eE[m]; }
          if (lane == 0) { sn += enS; se += eES; }
          sn = wsum(sn); se = wsum(se);
          if (lane == 0) { sN[r] = sn; sE[r] = se; }
        }
      }
    }
    __syncthreads();   // B1

    // ---- S2a: resolve stab/break(t-1); absorb; compute alp/a_s ----
    int stab_prev = 0;
    if (t > 0) {
      stab_prev = (c_mx > STABT) ? 1 : 0;
      if (!(sqrtf(c_es) > STOPE)) broke = true;
      if (stab_prev) {
        { const int j = tid; float bj = bb[j];
          vv[j] += EPSI * __logf(bj + TINY);
          if (j < KC) ww[j] *= __powf(fmaxf(bj, TINY), FIM1);
          bb[j] = 1.f; }
        if (tid == 0) { float bs = bb[KC]; vv[KC] += EPSI * __logf(bs + TINY); bb[KC] = 1.f; }
        if (tid < RPW) kap[tid] *= a_s[tid];     // a(t-1), pre-overwrite
      }
    }
    if (broke) { stabled = stab_prev; break; }   // uniform across grid
    if (tid < RPW) {
      float sp = stab_prev ? (sN[tid] + TINY * sE[tid]) : sN[tid];
      float al = PA / sp;
      alp[tid] = al;
      a_s[tid] = al / kap[tid];
    }
    __syncthreads();   // B2

    // ---- S2b: amax, zero next parity, register col dot -> atomicAdds ----
    if (wid == 0) {
      float v = (lane < RPW) ? a_s[lane] : 0.f;
      v = wmaxf(v);
      if (lane == 0) AST(&amaxa[p2 * NWG + wg], v);
    }
    {
      // zero own-batch slice of NEXT parity: 64 WGs x 256 floats + 32 tail
      float* zb = &colsum[pn * PARF + bat * REP * KP1];
      if (tid < 256) AST(&zb[slab * 256 + tid], 0.f);
      if (slab == 63 && tid >= 256 && tid < 288) AST(&zb[16384 + (tid - 256)], 0.f);
    }
    {
      float av[RPW];
      const float4* ap4 = (const float4*)alp;
#pragma unroll
      for (int i = 0; i < RPW / 4; ++i) *(float4*)&av[i * 4] = ap4[i];
      float acc = 0.f;
#pragma unroll
      for (int r = 0; r < RPW; ++r) acc += Kc[r] * av[r];
      float* cb = &colsum[p * PARF + (bat * REP + rep) * KP1];
      (void)AADD(&cb[tid], acc);
      if (tid == 0) {
        float acc2 = 0.f;
#pragma unroll
        for (int r = 0; r < RPW; ++r) acc2 += av[r];
        (void)AADD(&cb[KC], acc2);               // slack column: K = 1
      }
    }
    asm volatile("s_waitcnt vmcnt(0)" ::: "memory");
    __syncthreads();   // B3
    if (tid == 0) (void)AADD(&leafA[(bat * 4 + (slab >> 4)) * 16], 1u);

    // ---- S3: lane-parallel leaf poll (4 leaves x 16 WGs per batch) ----
    if (tid < 4) {
      const unsigned want = 16u * (unsigned)(t + 1);
      unsigned* lf = &leafA[(bat * 4 + tid) * 16];
      while (ALD(lf) < want) __builtin_amdgcn_s_sleep(1);
    }
    __syncthreads();   // B4

    // ---- S4: read colsum, bn, err partials, commit bb, build ev(t+1) ----
    const float* cb0 = &colsum[p * PARF + bat * REP * KP1];
    float esq_c, mx_c;
    {
      const int j = tid;
      float tot = 0.f;
#pragma unroll
      for (int i = 0; i < REP; ++i) tot += ALD(&cb0[i * KP1 + j]);
      float E = __expf(vv[j] * IEPS);
      float bn0 = __powf(fmaxf(PBR / (E * tot), TINY), FI) * ww[j];
      float d = bn0 - bb[j];
      esq_c = d * d; mx_c = bn0;
      bb[j] = bn0; evE[j] = E; evn[j] = E * bn0;
    }
    if (tid == 0) {
      float tot = 0.f;
#pragma unroll
      for (int i = 0; i < REP; ++i) tot += ALD(&cb0[i * KP1 + KC]);
      float E = __expf(vv[KC] * IEPS);
      float bn1 = PBS / (E * tot);
      float d = bn1 - bb[KC];
      esq_c += d * d; mx_c = fmaxf(mx_c, bn1);
      bb[KC] = bn1; evE[KC] = E; evn[KC] = E * bn1;
    }
    esq_c = wsum(esq_c); mx_c = wmaxf(mx_c);
    if (lane == 0) { redS[wid] = esq_c; redM[wid] = mx_c; }
    __syncthreads();   // B5

    // ---- S5: owner's wave 7 publishes consensus(t), tag t+1 ----
    if (slab == 0 && wid == NW - 1) {
      float am = ALD(&amaxa[p2 * NWG + bat * 64 + lane]);
      am = wmaxf(am);
      if (lane == 0) {
        float est = 0.f, mxt = am;
#pragma unroll
        for (int i = 0; i < NW; ++i) { est += redS[i]; mxt = fmaxf(mxt, redM[i]); }
        const unsigned long long tagw = (unsigned long long)(unsigned)(t + 1) << 32;
        const unsigned long long e64 = tagw | (unsigned long long)__float_as_uint(est);
        const unsigned long long m64 = tagw | (unsigned long long)__float_as_uint(mxt);
        const int slot = (t + 1) & 3;
#pragma unroll
        for (int g = 0; g < 8; ++g) {
          unsigned long long* ln = &cons[(size_t)((bat * 4 + slot) * 8 + g) * 8];
          AST(&ln[0], e64); AST(&ln[1], m64);
        }
      }
    }
    p = pn;
  }

  // ---- full-run: resolve consensus(ITMAX-1) for stabled + final absorption ----
  if (!broke) {
    if (tid < 4) {
      const unsigned tag = (unsigned)ITMAX;
      const int slot = ITMAX & 3;
      const unsigned long long* ln = &cons[(size_t)((tid * 4 + slot) * 8 + grp) * 8];
      unsigned long long m;
      for (;;) { m = ALD(&ln[1]); if ((unsigned)(m >> 32) == tag) break;
                 __builtin_amdgcn_s_sleep(1); }
      redM[tid] = __uint_as_float((unsigned)m);
    }
    __syncthreads();
    float mxt = fmaxf(fmaxf(redM[0], redM[1]), fmaxf(redM[2], redM[3]));
    stabled = (mxt > STABT) ? 1 : 0;
    if (stabled) {
      { const int j = tid; float bj = bb[j];
        vv[j] += EPSI * __logf(bj + TINY); bb[j] = 1.f; }
      if (tid == 0) { float bs = bb[KC]; vv[KC] += EPSI * __logf(bs + TINY); bb[KC] = 1.f; }
      if (tid < RPW) kap[tid] *= a_s[tid];
      __syncthreads();
    }
  }

  // ---- done: everyone signals; only scratch-overlapping WGs wait ----
  __syncthreads();
  if (tid == 0) (void)AADD(done, 1u);
  if (bat == 3 && slab >= 51) {     // scratch overlaps out rows >= 7807
    if (tid == 0) { while (ALD(done) < (unsigned)NWG) __builtin_amdgcn_s_sleep(2); }
    __syncthreads();
  }

  // ---------------- final: plan = (stabled ? Q : a*Q*b^T) * n ----------------
  for (int j = tid; j < KP1; j += NTHR) evE[j] = __expf(vv[j] * IEPS);
  __syncthreads();
  if (wid >= 1) {
    float eE[8], bbf[8];
#pragma unroll
    for (int m = 0; m < 8; ++m) {
      const int j = lane + (m << 6);
      eE[m] = evE[j]; bbf[m] = bb[j];
    }
#pragma unroll
    for (int q = 0; q < 5; ++q) {
      const int r = rs + q;
      if (r < RPW) {
        float* op = out + (rowg0 + (size_t)r) * KC;
        const float kr = kap[r], ar = a_s[r];
#pragma unroll
        for (int m = 0; m < 8; ++m) {
          float Q = kr * Kr[q][m] * eE[m];
          op[lane + (m << 6)] = (stabled ? Q : (ar * Q * bbf[m])) * 2048.0f;
        }
      }
    }
  }
}

extern "C" void kernel_launch(void* const* d_in, const int* in_sizes, int n_in,
                              void* d_out, int out_size, void* d_ws, size_t ws_size,
                              hipStream_t stream) {
  (void)in_sizes; (void)n_in; (void)out_size; (void)ws_size;
  const float* logits = (const float*)d_in[0];
  float* out = (float*)d_out;
  float* scr = out + SCR_OFF;
  (void)hipMemsetAsync(d_ws, 0, WS_ZERO, stream);
  (void)hipMemsetAsync(scr, 0, SCR_FLOATS * sizeof(float), stream);
  sinkhorn_kernel<<<dim3(NWG), dim3(NTHR), 0, stream>>>(
      logits, out, (unsigned char*)d_ws, scr);
}

// Round 13
// 364.524 us; speedup vs baseline: 1.1060x; 1.1060x over previous
//
#include <hip/hip_runtime.h>
#include <math.h>

// SemiCurrSinkhornKnopp_stable on MI355X: persistent kernel, no global barrier.
// R13 = R11 exact revert (R12's REP=32 regressed: +10MB zeroing writes, 4x
// reader line-touches; per-line RMW serialization was NOT the dominant leg).
// Structure: register-cached K (row frags Kr[5][8] on waves 1-7, col frag
// Kc[32] per thread), consensus poll overlapped with row pass via wave
// specialization + dual-representation row sums, tagged 4-deep consensus ring,
// per-batch lane-parallel leaf arrive, REP=8 colsum replica atomicAdd into LLC
// scratch carved from d_out tail (triple-buffered parities).
// Per-iteration chain: row dots/poll (parallel) -> pick rep -> col adds ->
// vmcnt drain -> leaf arrive -> poll -> colsum read -> bn -> publish.
// ~3.5 serial LLC legs/iter ~= the structural floor for this dataflow.

#define NWG   256
#define NTHR  512
#define NW    8
#define NROW  2048
#define KC    512
#define KP1   513
#define RPW   32
#define REP   8
#define PARF  (4 * REP * KP1)   // 16416 floats per parity
#define EPSI  0.1f
#define IEPS  10.0f
#define FI    0.90909090909090906f
#define FIM1  (-0.09090909090909094f)
#define TINY  1.1920928955078125e-07f
#define PA    (1.0f/2048.0f)
#define PBR   (0.5f/512.0f)
#define PBS   0.5f
#define STABT 1.0e8f
#define STOPE 1.0e-6f
#define ITMAX 50

#define AST(p, v)  __hip_atomic_store((p), (v), __ATOMIC_RELAXED, __HIP_MEMORY_SCOPE_AGENT)
#define ALD(p)     __hip_atomic_load((p), __ATOMIC_RELAXED, __HIP_MEMORY_SCOPE_AGENT)
#define AADD(p, v) __hip_atomic_fetch_add((p), (v), __ATOMIC_RELAXED, __HIP_MEMORY_SCOPE_AGENT)

// d_ws layout: leaf @0 (16x64B) | cons @2048 (4b x 4slot x 8grp x 64B = 8192)
//              amaxa @10240 ([2][256] f32) | done @12288
#define WS_ZERO 12352

// colsum scratch carved from d_out tail: [3][4][REP][KP1] floats
#define TOT_OUT    4194304
#define SCR_FLOATS (3 * PARF)            // 49248
#define SCR_OFF    (TOT_OUT - SCR_FLOATS)

__device__ __forceinline__ float wsum(float v) {
#pragma unroll
  for (int m = 32; m > 0; m >>= 1) v += __shfl_xor(v, m, 64);
  return v;
}
__device__ __forceinline__ float wmaxf(float v) {
#pragma unroll
  for (int m = 32; m > 0; m >>= 1) v = fmaxf(v, __shfl_xor(v, m, 64));
  return v;
}

__global__ __launch_bounds__(NTHR)
void sinkhorn_kernel(const float* __restrict__ logits, float* out,
                     unsigned char* ws, float* colsum) {
  const int tid  = threadIdx.x;
  const int wg   = blockIdx.x;
  const int lane = tid & 63;
  const int wid  = tid >> 6;
  const int bat  = wg >> 6;
  const int slab = wg & 63;
  const int rep  = slab & (REP - 1);
  const int grp  = wg & 7;

  unsigned*           leafA = (unsigned*)(ws);
  unsigned long long* cons  = (unsigned long long*)(ws + 2048);
  float*              amaxa = (float*)(ws + 10240);
  unsigned*           done  = (unsigned*)(ws + 12288);

  __shared__ float Klds[RPW][KP1];
  __shared__ float evn[KP1], evE[KP1], vv[KP1], bb[KP1], ww[KC];
  __shared__ __align__(16) float alp[RPW];
  __shared__ float sN[RPW], sE[RPW], a_s[RPW], kap[RPW];
  __shared__ float redS[NW], redM[NW];
  __shared__ float c_es, c_mx;

  // ---------------- init own-batch state ----------------
  for (int j = tid; j < KP1; j += NTHR) {
    vv[j] = 0.f; bb[j] = 1.f / 513.f;
    evE[j] = 1.f; evn[j] = 1.f / 513.f;          // E(vv=0)=1
  }
  for (int j = tid; j < KC; j += NTHR) ww[j] = 1.f;
  if (tid < RPW) { kap[tid] = 1.f; a_s[tid] = 0.f; alp[tid] = 0.f; }

  // ---------------- build K = softmax(logits)^10 in LDS ----------------
  const size_t rowg0 = (size_t)bat * NROW + (size_t)slab * RPW;
  for (int r = wid; r < RPW; r += NW) {
    const float* lp = logits + (rowg0 + (size_t)r) * KC;
    float x[8];
    float mx = -INFINITY;
#pragma unroll
    for (int m = 0; m < 8; ++m) { x[m] = lp[lane + (m << 6)]; mx = fmaxf(mx, x[m]); }
    mx = wmaxf(mx);
    float sm = 0.f;
#pragma unroll
    for (int m = 0; m < 8; ++m) sm += expf(x[m] - mx);
    sm = wsum(sm);
    float lse = mx + logf(sm);
#pragma unroll
    for (int m = 0; m < 8; ++m) Klds[r][lane + (m << 6)] = expf((x[m] - lse) * IEPS);
    if (lane == 0) Klds[r][KC] = 1.f;
  }
  __syncthreads();

  // ---------------- cache K in registers (iteration-invariant) ----------------
  const int rs = (wid - 1) * 5;     // rows for waves 1..7 (5,5,5,5,5,5,2)
  float Kr[5][8];
  if (wid >= 1) {
#pragma unroll
    for (int q = 0; q < 5; ++q) {
      const int r = rs + q;
      if (r < RPW) {
#pragma unroll
        for (int m = 0; m < 8; ++m) Kr[q][m] = Klds[r][lane + (m << 6)];
      }
    }
  }
  float Kc[RPW];                    // column `tid` (tid<512; col 512 is all-ones)
#pragma unroll
  for (int r = 0; r < RPW; ++r) Kc[r] = Klds[r][tid];

  int stabled = 0;
  int p = 0;
  bool broke = false;

  for (int t = 0; t < ITMAX; ++t) {
    const int p2 = t & 1;
    const int pn = (p == 2) ? 0 : (p + 1);

    // ---- S1: wave0 polls cons(t-1) || waves1-7 register dual-rep row dots ----
    if (wid == 0) {
      if (t > 0) {
        const unsigned tag = (unsigned)t;
        const int slot = t & 3;
        const unsigned long long* ln =
            &cons[(size_t)(((lane & 3) * 4 + slot) * 8 + grp) * 8];
        unsigned long long e = 0, m = 0;
        bool rdy = (lane >= 4);
        for (;;) {
          if (!rdy) {
            e = ALD(&ln[0]); m = ALD(&ln[1]);
            rdy = ((unsigned)(e >> 32) == tag) && ((unsigned)(m >> 32) == tag);
          }
          if (__all(rdy)) break;
          __builtin_amdgcn_s_sleep(1);
        }
        float ef = (lane < 4) ? __uint_as_float((unsigned)e) : 0.f;
        float mf = (lane < 4) ? __uint_as_float((unsigned)m) : 0.f;
        ef += __shfl_xor(ef, 1, 64); ef += __shfl_xor(ef, 2, 64);
        mf = fmaxf(mf, __shfl_xor(mf, 1, 64)); mf = fmaxf(mf, __shfl_xor(mf, 2, 64));
        if (lane == 0) { c_es = ef; c_mx = mf; }
      }
    } else {
      float en[8], eE[8];
#pragma unroll
      for (int m = 0; m < 8; ++m) {
        const int j = lane + (m << 6);
        en[m] = evn[j]; eE[m] = evE[j];
      }
      const float enS = evn[KC], eES = evE[KC];    // slack (K=1), broadcast
#pragma unroll
      for (int q = 0; q < 5; ++q) {
        const int r = rs + q;
        if (r < RPW) {
          float sn = 0.f, se = 0.f;
#pragma unroll
          for (int m = 0; m < 8; ++m) { sn += Kr[q][m] * en[m]; se += Kr[q][m] * eE[m]; }
          if (lane == 0) { sn += enS; se += eES; }
          sn = wsum(sn); se = wsum(se);
          if (lane == 0) { sN[r] = sn; sE[r] = se; }
        }
      }
    }
    __syncthreads();   // B1

    // ---- S2a: resolve stab/break(t-1); absorb; compute alp/a_s ----
    int stab_prev = 0;
    if (t > 0) {
      stab_prev = (c_mx > STABT) ? 1 : 0;
      if (!(sqrtf(c_es) > STOPE)) broke = true;
      if (stab_prev) {
        { const int j = tid; float bj = bb[j];
          vv[j] += EPSI * __logf(bj + TINY);
          if (j < KC) ww[j] *= __powf(fmaxf(bj, TINY), FIM1);
          bb[j] = 1.f; }
        if (tid == 0) { float bs = bb[KC]; vv[KC] += EPSI * __logf(bs + TINY); bb[KC] = 1.f; }
        if (tid < RPW) kap[tid] *= a_s[tid];     // a(t-1), pre-overwrite
      }
    }
    if (broke) { stabled = stab_prev; break; }   // uniform across grid
    if (tid < RPW) {
      float sp = stab_prev ? (sN[tid] + TINY * sE[tid]) : sN[tid];
      float al = PA / sp;
      alp[tid] = al;
      a_s[tid] = al / kap[tid];
    }
    __syncthreads();   // B2

    // ---- S2b: amax, zero next parity, register col dot -> atomicAdds ----
    if (wid == 0) {
      float v = (lane < RPW) ? a_s[lane] : 0.f;
      v = wmaxf(v);
      if (lane == 0) AST(&amaxa[p2 * NWG + wg], v);
    }
    {
      float* zb = &colsum[pn * PARF + bat * REP * KP1];
      if (tid < 64) AST(&zb[slab * 64 + tid], 0.f);
      if (slab == 0 && tid >= 64 && tid < 72) AST(&zb[4096 + (tid - 64)], 0.f);
    }
    {
      float av[RPW];
      const float4* ap4 = (const float4*)alp;
#pragma unroll
      for (int i = 0; i < RPW / 4; ++i) *(float4*)&av[i * 4] = ap4[i];
      float acc = 0.f;
#pragma unroll
      for (int r = 0; r < RPW; ++r) acc += Kc[r] * av[r];
      float* cb = &colsum[p * PARF + (bat * REP + rep) * KP1];
      (void)AADD(&cb[tid], acc);
      if (tid == 0) {
        float acc2 = 0.f;
#pragma unroll
        for (int r = 0; r < RPW; ++r) acc2 += av[r];
        (void)AADD(&cb[KC], acc2);               // slack column: K = 1
      }
    }
    asm volatile("s_waitcnt vmcnt(0)" ::: "memory");
    __syncthreads();   // B3
    if (tid == 0) (void)AADD(&leafA[(bat * 4 + (slab >> 4)) * 16], 1u);

    // ---- S3: lane-parallel leaf poll (4 leaves x 16 WGs per batch) ----
    if (tid < 4) {
      const unsigned want = 16u * (unsigned)(t + 1);
      unsigned* lf = &leafA[(bat * 4 + tid) * 16];
      while (ALD(lf) < want) __builtin_amdgcn_s_sleep(1);
    }
    __syncthreads();   // B4

    // ---- S4: read colsum, bn, err partials, commit bb, build ev(t+1) ----
    const float* cb0 = &colsum[p * PARF + bat * REP * KP1];
    float esq_c, mx_c;
    {
      const int j = tid;
      float tot = 0.f;
#pragma unroll
      for (int i = 0; i < REP; ++i) tot += ALD(&cb0[i * KP1 + j]);
      float E = __expf(vv[j] * IEPS);
      float bn0 = __powf(fmaxf(PBR / (E * tot), TINY), FI) * ww[j];
      float d = bn0 - bb[j];
      esq_c = d * d; mx_c = bn0;
      bb[j] = bn0; evE[j] = E; evn[j] = E * bn0;
    }
    if (tid == 0) {
      float tot = 0.f;
#pragma unroll
      for (int i = 0; i < REP; ++i) tot += ALD(&cb0[i * KP1 + KC]);
      float E = __expf(vv[KC] * IEPS);
      float bn1 = PBS / (E * tot);
      float d = bn1 - bb[KC];
      esq_c += d * d; mx_c = fmaxf(mx_c, bn1);
      bb[KC] = bn1; evE[KC] = E; evn[KC] = E * bn1;
    }
    esq_c = wsum(esq_c); mx_c = wmaxf(mx_c);
    if (lane == 0) { redS[wid] = esq_c; redM[wid] = mx_c; }
    __syncthreads();   // B5

    // ---- S5: owner's wave 7 publishes consensus(t), tag t+1 ----
    if (slab == 0 && wid == NW - 1) {
      float am = ALD(&amaxa[p2 * NWG + bat * 64 + lane]);
      am = wmaxf(am);
      if (lane == 0) {
        float est = 0.f, mxt = am;
#pragma unroll
        for (int i = 0; i < NW; ++i) { est += redS[i]; mxt = fmaxf(mxt, redM[i]); }
        const unsigned long long tagw = (unsigned long long)(unsigned)(t + 1) << 32;
        const unsigned long long e64 = tagw | (unsigned long long)__float_as_uint(est);
        const unsigned long long m64 = tagw | (unsigned long long)__float_as_uint(mxt);
        const int slot = (t + 1) & 3;
#pragma unroll
        for (int g = 0; g < 8; ++g) {
          unsigned long long* ln = &cons[(size_t)((bat * 4 + slot) * 8 + g) * 8];
          AST(&ln[0], e64); AST(&ln[1], m64);
        }
      }
    }
    p = pn;
  }

  // ---- full-run: resolve consensus(ITMAX-1) for stabled + final absorption ----
  if (!broke) {
    if (tid < 4) {
      const unsigned tag = (unsigned)ITMAX;
      const int slot = ITMAX & 3;
      const unsigned long long* ln = &cons[(size_t)((tid * 4 + slot) * 8 + grp) * 8];
      unsigned long long m;
      for (;;) { m = ALD(&ln[1]); if ((unsigned)(m >> 32) == tag) break;
                 __builtin_amdgcn_s_sleep(1); }
      redM[tid] = __uint_as_float((unsigned)m);
    }
    __syncthreads();
    float mxt = fmaxf(fmaxf(redM[0], redM[1]), fmaxf(redM[2], redM[3]));
    stabled = (mxt > STABT) ? 1 : 0;
    if (stabled) {
      { const int j = tid; float bj = bb[j];
        vv[j] += EPSI * __logf(bj + TINY); bb[j] = 1.f; }
      if (tid == 0) { float bs = bb[KC]; vv[KC] += EPSI * __logf(bs + TINY); bb[KC] = 1.f; }
      if (tid < RPW) kap[tid] *= a_s[tid];
      __syncthreads();
    }
  }

  // ---- done: everyone signals; only scratch-overlapping WGs wait ----
  __syncthreads();
  if (tid == 0) (void)AADD(done, 1u);
  if (bat == 3 && slab >= 60) {
    if (tid == 0) { while (ALD(done) < (unsigned)NWG) __builtin_amdgcn_s_sleep(2); }
    __syncthreads();
  }

  // ---------------- final: plan = (stabled ? Q : a*Q*b^T) * n ----------------
  for (int j = tid; j < KP1; j += NTHR) evE[j] = __expf(vv[j] * IEPS);
  __syncthreads();
  if (wid >= 1) {
    float eE[8], bbf[8];
#pragma unroll
    for (int m = 0; m < 8; ++m) {
      const int j = lane + (m << 6);
      eE[m] = evE[j]; bbf[m] = bb[j];
    }
#pragma unroll
    for (int q = 0; q < 5; ++q) {
      const int r = rs + q;
      if (r < RPW) {
        float* op = out + (rowg0 + (size_t)r) * KC;
        const float kr = kap[r], ar = a_s[r];
#pragma unroll
        for (int m = 0; m < 8; ++m) {
          float Q = kr * Kr[q][m] * eE[m];
          op[lane + (m << 6)] = (stabled ? Q : (ar * Q * bbf[m])) * 2048.0f;
        }
      }
    }
  }
}

extern "C" void kernel_launch(void* const* d_in, const int* in_sizes, int n_in,
                              void* d_out, int out_size, void* d_ws, size_t ws_size,
                              hipStream_t stream) {
  (void)in_sizes; (void)n_in; (void)out_size; (void)ws_size;
  const float* logits = (const float*)d_in[0];
  float* out = (float*)d_out;
  float* scr = out + SCR_OFF;
  (void)hipMemsetAsync(d_ws, 0, WS_ZERO, stream);
  (void)hipMemsetAsync(scr, 0, SCR_FLOATS * sizeof(float), stream);
  sinkhorn_kernel<<<dim3(NWG), dim3(NTHR), 0, stream>>>(
      logits, out, (unsigned char*)d_ws, scr);
}